// Round 3
// baseline (1244.032 us; speedup 1.0000x reference)
//
#include <hip/hip_runtime.h>
#include <hip/hip_bf16.h>

// WindowCrossAttention fused kernel for MI355X (gfx950).
// B=4096 windows, N=49 tokens, C=256, H=8 heads, d=32.
// One block per window; 8 waves (wave = head); bf16 MFMA 16x16x32.
//
// R3: LDS 135.7KB -> 79.4KB => 2 blocks/CU (R2 counters: latency-bound,
// Occupancy 24%, MfmaUtil 10%, HBM 10%).
//  - unpadded [49][256] tiles; fragment reads over-run harmlessly (row-isolated
//    garbage / masked cols / reg-zeroed V tokens)
//  - Q transposed via 3.5KB per-wave scratch, lives in registers (no Q region)
//  - P tiles overlay x+K after their last reads; LN red overlays VT
//  - VT epilogue packed b64 stores; launch_bounds(512,4) caps VGPR at 128

typedef __attribute__((ext_vector_type(8))) short bf16x8;   // 8 bf16 = 4 VGPR
typedef __attribute__((ext_vector_type(4))) float f32x4;

#define NTOK 49
#define CCH  256

// LDS regions (bytes)
#define R_A       0       // [49][256]bf16 swz512: x / y staging -> P slots w0-3 -> attn-out
#define R_B       25088   // [49][256]bf16 swz512: K -> P slots w4-7
#define R_C       50176   // [256][56]bf16 VT (stride 112) / per-wave Q scratch / LN red+mu
#define QS_STRIDE 3584    // per-wave Q scratch slice in R_C
#define P_STRIDE  6272    // per-wave P slot ([49][128B]) spanning R_A+R_B
#define VT_STRIDE 112
#define LDS_TOT   79360   // R_C + 28672 + 512 guard for scratch over-run reads

__device__ __forceinline__ unsigned f2bf(float f) {
  unsigned u = __float_as_uint(f);
  return (u + 0x7FFFu + ((u >> 16) & 1u)) >> 16;   // RNE fp32->bf16
}
__device__ __forceinline__ int swz512(int r, int cb) { return r * 512 + (cb ^ ((r & 7) << 4)); }
__device__ __forceinline__ int swz128(int r, int cb) { return r * 128 + (cb ^ ((r & 7) << 4)); }
__device__ __forceinline__ int swz64 (int r, int cb) { return r * 64  + (cb ^ ((r & 3) << 4)); }

// 64x32 tile of out = A[49(read as 64)][256] @ W^T; W row-major [co][ci] feeds
// the B-fragment directly. Over-run rows (>=49) read garbage: row-isolated.
__device__ __forceinline__ void gemm256(const char* sm, int base_a,
                                        const unsigned short* __restrict__ W,
                                        int w, int r16, int g, f32x4 acc[4][2]) {
#pragma unroll
  for (int k0 = 0; k0 < 8; ++k0) {
    const int kk = k0 * 32 + g * 8;
    bf16x8 a[4], bb[2];
#pragma unroll
    for (int mt = 0; mt < 4; ++mt)
      a[mt] = *(const bf16x8*)(sm + base_a + swz512(mt * 16 + r16, kk * 2));
#pragma unroll
    for (int nt = 0; nt < 2; ++nt)
      bb[nt] = *(const bf16x8*)(W + (w * 32 + nt * 16 + r16) * CCH + kk);
#pragma unroll
    for (int mt = 0; mt < 4; ++mt)
#pragma unroll
      for (int nt = 0; nt < 2; ++nt)
        acc[mt][nt] = __builtin_amdgcn_mfma_f32_16x16x32_bf16(a[mt], bb[nt], acc[mt][nt], 0, 0, 0);
  }
}

__device__ __forceinline__ void stage49(char* sm, const float* __restrict__ src, int tid) {
  // [49][256] fp32 -> LDS bf16 swizzled (exactly 49 rows, no pad)
#pragma unroll 2
  for (int idx = tid; idx < NTOK * 64; idx += 512) {
    int r = idx >> 6;
    int c = (idx & 63) << 2;
    float4 v = *(const float4*)(src + r * CCH + c);
    uint2 pk;
    pk.x = f2bf(v.x) | (f2bf(v.y) << 16);
    pk.y = f2bf(v.z) | (f2bf(v.w) << 16);
    *(uint2*)(sm + R_A + swz512(r, c * 2)) = pk;
  }
}

// ---------------- prep kernels ----------------

__global__ void prep_weights(const float* __restrict__ wq, const float* __restrict__ wk,
                             const float* __restrict__ wv, const float* __restrict__ pw,
                             unsigned short* __restrict__ o) {
  int i = blockIdx.x * 256 + threadIdx.x;
  o[i]          = (unsigned short)f2bf(wq[i]);
  o[65536 + i]  = (unsigned short)f2bf(wk[i]);
  o[131072 + i] = (unsigned short)f2bf(wv[i]);
  o[196608 + i] = (unsigned short)f2bf(pw[i]);
}

__global__ void prep_bias(const float* __restrict__ btab, const int* __restrict__ rpi,
                          float* __restrict__ bt) {
  int h = blockIdx.x;
  for (int i = threadIdx.x; i < NTOK * NTOK; i += 256)
    bt[h * NTOK * NTOK + i] = btab[rpi[i] * 8 + h];
}

// ---------------- main fused kernel ----------------

__global__ __launch_bounds__(512, 4) void wca_main(
    const float* __restrict__ x, const float* __restrict__ y,
    const unsigned short* __restrict__ wbf,
    const float* __restrict__ wq_b, const float* __restrict__ wk_b,
    const float* __restrict__ wv_b, const float* __restrict__ proj_b,
    const float* __restrict__ bt, const float* __restrict__ mask,
    const float* __restrict__ ln_g, const float* __restrict__ ln_b,
    float* __restrict__ out) {
  __shared__ __align__(16) char sm[LDS_TOT];
  const int tid = threadIdx.x;
  const int lane = tid & 63;
  const int w = tid >> 6;           // wave = head
  const int r16 = lane & 15;
  const int g = lane >> 4;
  const int b = blockIdx.x;
  const size_t bbase = (size_t)b * NTOK * CCH;
  const float* xb = x + bbase;
  const float* yb = y + bbase;

  // ---- phase 1: stage x ----
  stage49(sm, xb, tid);
  __syncthreads();   // #1

  // ---- phase 2: Q = x @ Wq^T + bq -> per-wave scratch (R_C) ----
  {
    f32x4 acc[4][2];
#pragma unroll
    for (int i = 0; i < 4; ++i) { acc[i][0] = (f32x4)(0.0f); acc[i][1] = (f32x4)(0.0f); }
    gemm256(sm, R_A, wbf, w, r16, g, acc);
    char* qs = sm + R_C + w * QS_STRIDE;   // [49 rows][32 dims] stride 64B, swz64
#pragma unroll
    for (int nt = 0; nt < 2; ++nt) {
      float bv = wq_b[w * 32 + nt * 16 + r16];
      int dim_l = nt * 16 + r16;
#pragma unroll
      for (int mt = 0; mt < 4; ++mt)
#pragma unroll
        for (int r = 0; r < 4; ++r) {
          int row = mt * 16 + g * 4 + r;
          if (row < NTOK)
            *(unsigned short*)(qs + swz64(row, dim_l * 2)) =
                (unsigned short)f2bf(acc[mt][nt][r] + bv);
        }
    }
  }
  __syncthreads();   // #2: x dead (A reusable); scratch writes visible (to self)

  // qf: own head's Q as A-fragments (kept in registers for the whole kernel)
  bf16x8 qf[4];
  {
    const char* qs = sm + R_C + w * QS_STRIDE;
#pragma unroll
    for (int mt = 0; mt < 4; ++mt)
      qf[mt] = *(const bf16x8*)(qs + swz64(mt * 16 + r16, g * 16));
  }
  stage49(sm, yb, tid);   // y over x (concurrent with qf reads: different regions)
  __syncthreads();   // #3: y staged; all qf reads done (R_C reusable for VT)

  // ---- phase 4: K -> R_B ; V -> VT (R_C, [dim][token] stride 112B) ----
  {
    f32x4 acc[4][2];
#pragma unroll
    for (int i = 0; i < 4; ++i) { acc[i][0] = (f32x4)(0.0f); acc[i][1] = (f32x4)(0.0f); }
    gemm256(sm, R_A, wbf + 65536, w, r16, g, acc);
#pragma unroll
    for (int nt = 0; nt < 2; ++nt) {
      int col = w * 32 + nt * 16 + r16;
      float bv = wk_b[col];
#pragma unroll
      for (int mt = 0; mt < 4; ++mt)
#pragma unroll
        for (int r = 0; r < 4; ++r) {
          int row = mt * 16 + g * 4 + r;
          if (row < NTOK)
            *(unsigned short*)(sm + R_B + swz512(row, col * 2)) =
                (unsigned short)f2bf(acc[mt][nt][r] + bv);
        }
    }
  }
  {
    f32x4 acc[4][2];
#pragma unroll
    for (int i = 0; i < 4; ++i) { acc[i][0] = (f32x4)(0.0f); acc[i][1] = (f32x4)(0.0f); }
    gemm256(sm, R_A, wbf + 131072, w, r16, g, acc);
#pragma unroll
    for (int nt = 0; nt < 2; ++nt) {
      int dim = w * 32 + nt * 16 + r16;
      float bv = wv_b[dim];
#pragma unroll
      for (int mt = 0; mt < 3; ++mt) {   // tokens mt*16+g*4 .. +3 all < 49 -> packed b64
        int t0 = mt * 16 + g * 4;
        uint2 pk;
        pk.x = f2bf(acc[mt][nt][0] + bv) | (f2bf(acc[mt][nt][1] + bv) << 16);
        pk.y = f2bf(acc[mt][nt][2] + bv) | (f2bf(acc[mt][nt][3] + bv) << 16);
        *(uint2*)(sm + R_C + dim * VT_STRIDE + t0 * 2) = pk;
      }
      if (g == 0)   // mt=3: only token 48 valid
        *(unsigned short*)(sm + R_C + dim * VT_STRIDE + 48 * 2) =
            (unsigned short)f2bf(acc[3][nt][0] + bv);
    }
  }
  __syncthreads();   // #4: K/VT visible; y dead

  // ---- phase 5: QK^T + bias + softmax (all in registers) ----
  float rs[4][4];
  f32x4 s[4][4];
  {
#pragma unroll
    for (int i = 0; i < 4; ++i)
#pragma unroll
      for (int j = 0; j < 4; ++j) s[i][j] = (f32x4)(0.0f);
    const int kk = w * 32 + g * 8;
    bf16x8 kf[4];
#pragma unroll
    for (int nt = 0; nt < 4; ++nt)
      kf[nt] = *(const bf16x8*)(sm + R_B + swz512(nt * 16 + r16, kk * 2));
#pragma unroll
    for (int mt = 0; mt < 4; ++mt)
#pragma unroll
      for (int nt = 0; nt < 4; ++nt)
        s[mt][nt] = __builtin_amdgcn_mfma_f32_16x16x32_bf16(qf[mt], kf[nt], s[mt][nt], 0, 0, 0);

    const float scale = 0.17677669529663687f;   // 1/sqrt(32)
    const float* bp = bt + w * (NTOK * NTOK);
    const float* mp = mask + (size_t)(b & 63) * (NTOK * NTOK);
#pragma unroll
    for (int mt = 0; mt < 4; ++mt)
#pragma unroll
      for (int nt = 0; nt < 4; ++nt) {
        int col = nt * 16 + r16;
#pragma unroll
        for (int r = 0; r < 4; ++r) {
          int row = mt * 16 + g * 4 + r;
          float v = s[mt][nt][r] * scale;
          if (col < NTOK) { if (row < NTOK) v += bp[row * NTOK + col] + mp[row * NTOK + col]; }
          else v = -1e30f;
          s[mt][nt][r] = v;
        }
      }
#pragma unroll
    for (int mt = 0; mt < 4; ++mt)
#pragma unroll
      for (int r = 0; r < 4; ++r) {
        float m = fmaxf(fmaxf(s[mt][0][r], s[mt][1][r]), fmaxf(s[mt][2][r], s[mt][3][r]));
        m = fmaxf(m, __shfl_xor(m, 1)); m = fmaxf(m, __shfl_xor(m, 2));
        m = fmaxf(m, __shfl_xor(m, 4)); m = fmaxf(m, __shfl_xor(m, 8));
        float sum = 0.f;
#pragma unroll
        for (int nt = 0; nt < 4; ++nt) {
          float e = __expf(s[mt][nt][r] - m);
          s[mt][nt][r] = e;
          sum += e;
        }
        sum += __shfl_xor(sum, 1); sum += __shfl_xor(sum, 2);
        sum += __shfl_xor(sum, 4); sum += __shfl_xor(sum, 8);
        rs[mt][r] = 1.0f / sum;
      }
  }
  __syncthreads();   // #5: all kf reads + y-region reads done -> P may overlay A+B

  // P stores: per-wave [49][64]bf16 slot at w*P_STRIDE (cols>=49 are exact zeros)
  char* sa = sm + w * P_STRIDE;
#pragma unroll
  for (int mt = 0; mt < 4; ++mt)
#pragma unroll
    for (int r = 0; r < 4; ++r) {
      int row = mt * 16 + g * 4 + r;
      if (row < NTOK) {
#pragma unroll
        for (int nt = 0; nt < 4; ++nt) {
          int col = nt * 16 + r16;
          *(unsigned short*)(sa + swz128(row, col * 2)) = (unsigned short)f2bf(s[mt][nt][r]);
        }
      }
    }
  // no barrier: each wave reads only its own P slot (over-run reads harmless)

  // ---- phase 6: PV ----
  f32x4 o[4][2];
  {
#pragma unroll
    for (int i = 0; i < 4; ++i) { o[i][0] = (f32x4)(0.0f); o[i][1] = (f32x4)(0.0f); }
#pragma unroll
    for (int kk2 = 0; kk2 < 2; ++kk2) {
      bf16x8 pa[4], vb[2];
#pragma unroll
      for (int mt = 0; mt < 4; ++mt)
        pa[mt] = *(const bf16x8*)(sa + swz128(mt * 16 + r16, kk2 * 64 + g * 16));
#pragma unroll
      for (int nt = 0; nt < 2; ++nt) {
        int dim = w * 32 + nt * 16 + r16;
        bf16x8 v = *(const bf16x8*)(sm + R_C + dim * VT_STRIDE + kk2 * 64 + g * 16);
        if (kk2 == 1) {   // tokens 32+g*8+e ; zero garbage tokens >= 49 in regs
          int tb = 32 + g * 8;
#pragma unroll
          for (int e = 0; e < 8; ++e)
            if (tb + e >= NTOK) v[e] = 0;
        }
        vb[nt] = v;
      }
#pragma unroll
      for (int mt = 0; mt < 4; ++mt)
#pragma unroll
        for (int nt = 0; nt < 2; ++nt)
          o[mt][nt] = __builtin_amdgcn_mfma_f32_16x16x32_bf16(pa[mt], vb[nt], o[mt][nt], 0, 0, 0);
    }
  }
  __syncthreads();   // #6: all pa/vb reads done -> attn-out may overwrite A

  // attn-out (normalized) -> R_A [49][256] swz512
#pragma unroll
  for (int nt = 0; nt < 2; ++nt) {
    int col = w * 32 + nt * 16 + r16;
#pragma unroll
    for (int mt = 0; mt < 4; ++mt)
#pragma unroll
      for (int r = 0; r < 4; ++r) {
        int row = mt * 16 + g * 4 + r;
        if (row < NTOK)
          *(unsigned short*)(sm + R_A + swz512(row, col * 2)) =
              (unsigned short)f2bf(o[mt][nt][r] * rs[mt][r]);
      }
  }
  __syncthreads();   // #7: attn-out visible

  // ---- phase 7: proj + residual + LayerNorm ----
  {
    f32x4 acc[4][2];
#pragma unroll
    for (int i = 0; i < 4; ++i) { acc[i][0] = (f32x4)(0.0f); acc[i][1] = (f32x4)(0.0f); }
    gemm256(sm, R_A, wbf + 196608, w, r16, g, acc);
    float h[4][2][4];
#pragma unroll
    for (int nt = 0; nt < 2; ++nt) {
      int col = w * 32 + nt * 16 + r16;
      float pb = proj_b[col];
#pragma unroll
      for (int mt = 0; mt < 4; ++mt)
#pragma unroll
        for (int r = 0; r < 4; ++r) {
          int row = mt * 16 + g * 4 + r;
          float xv = (row < NTOK) ? xb[row * CCH + col] : 0.0f;
          h[mt][nt][r] = acc[mt][nt][r] + pb + xv;
        }
    }
    float* red = (float*)(sm + R_C);          // [49][8][2] f32 (VT dead)
    float* mus = (float*)(sm + R_C + 3200);   // [49][2] f32
#pragma unroll
    for (int mt = 0; mt < 4; ++mt)
#pragma unroll
      for (int r = 0; r < 4; ++r) {
        float a0 = h[mt][0][r], a1 = h[mt][1][r];
        float s1 = a0 + a1;
        float s2 = a0 * a0 + a1 * a1;
        s1 += __shfl_xor(s1, 1); s2 += __shfl_xor(s2, 1);
        s1 += __shfl_xor(s1, 2); s2 += __shfl_xor(s2, 2);
        s1 += __shfl_xor(s1, 4); s2 += __shfl_xor(s2, 4);
        s1 += __shfl_xor(s1, 8); s2 += __shfl_xor(s2, 8);
        int row = mt * 16 + g * 4 + r;
        if (r16 == 0 && row < NTOK) {
          red[(row * 8 + w) * 2 + 0] = s1;
          red[(row * 8 + w) * 2 + 1] = s2;
        }
      }
    __syncthreads();   // #8
    if (tid < NTOK) {
      float s1 = 0.f, s2 = 0.f;
#pragma unroll
      for (int ww = 0; ww < 8; ++ww) { s1 += red[(tid * 8 + ww) * 2]; s2 += red[(tid * 8 + ww) * 2 + 1]; }
      float mu = s1 * (1.0f / 256.0f);
      float var = s2 * (1.0f / 256.0f) - mu * mu;
      mus[tid * 2] = mu;
      mus[tid * 2 + 1] = rsqrtf(var + 1e-5f);
    }
    __syncthreads();   // #9
    float* op = out + bbase;
#pragma unroll
    for (int nt = 0; nt < 2; ++nt) {
      int col = w * 32 + nt * 16 + r16;
      float gg = ln_g[col], bb2 = ln_b[col];
#pragma unroll
      for (int mt = 0; mt < 4; ++mt)
#pragma unroll
        for (int r = 0; r < 4; ++r) {
          int row = mt * 16 + g * 4 + r;
          if (row < NTOK)
            op[row * CCH + col] = (h[mt][nt][r] - mus[row * 2]) * mus[row * 2 + 1] * gg + bb2;
        }
    }
  }
}

extern "C" void kernel_launch(void* const* d_in, const int* in_sizes, int n_in,
                              void* d_out, int out_size, void* d_ws, size_t ws_size,
                              hipStream_t stream) {
  const float* x      = (const float*)d_in[0];
  const float* y      = (const float*)d_in[1];
  const float* mask   = (const float*)d_in[2];
  const float* wq_w   = (const float*)d_in[3];
  const float* wq_b   = (const float*)d_in[4];
  const float* wk_w   = (const float*)d_in[5];
  const float* wk_b   = (const float*)d_in[6];
  const float* wv_w   = (const float*)d_in[7];
  const float* wv_b   = (const float*)d_in[8];
  const float* btab   = (const float*)d_in[9];
  const float* proj_w = (const float*)d_in[10];
  const float* proj_b = (const float*)d_in[11];
  const float* ln_g   = (const float*)d_in[12];
  const float* ln_b   = (const float*)d_in[13];
  const int*   rpi    = (const int*)d_in[14];

  unsigned short* wbf = (unsigned short*)d_ws;              // 4 * 256*256 bf16 = 512 KB
  float* bt = (float*)((char*)d_ws + 4 * 65536 * 2);        // [8][49][49] f32 = 76.8 KB

  prep_weights<<<256, 256, 0, stream>>>(wq_w, wk_w, wv_w, proj_w, wbf);
  prep_bias<<<8, 256, 0, stream>>>(btab, rpi, bt);
  wca_main<<<4096, 512, 0, stream>>>(x, y, wbf, wq_b, wk_b, wv_b, proj_b, bt, mask,
                                     ln_g, ln_b, (float*)d_out);
}